// Round 2
// baseline (561.333 us; speedup 1.0000x reference)
//
#include <hip/hip_runtime.h>

#define EL 512
#define NB 64
#define IMG (EL*EL)
#define HC 256   // stored half-spectrum width (complex) per row; col 0 packs (kx=0, kx=256)

__device__ __forceinline__ void sb(){ __builtin_amdgcn_sched_barrier(0); }

// ---------------- complex helpers ----------------
__device__ __forceinline__ float2 cadd(float2 a, float2 b){ return make_float2(a.x+b.x, a.y+b.y); }
__device__ __forceinline__ float2 csub(float2 a, float2 b){ return make_float2(a.x-b.x, a.y-b.y); }
__device__ __forceinline__ float2 cmul(float2 a, float2 b){ return make_float2(a.x*b.x - a.y*b.y, a.x*b.y + a.y*b.x); }

template<int SIGN> __device__ __forceinline__ float2 mulW4(float2 a);
template<> __device__ __forceinline__ float2 mulW4<-1>(float2 a){ return make_float2( a.y, -a.x); } // * -i
template<> __device__ __forceinline__ float2 mulW4< 1>(float2 a){ return make_float2(-a.y,  a.x); } // * +i

// 8-point DFT, SIGN=-1 forward, +1 inverse (unnormalized)
template<int SIGN>
__device__ __forceinline__ void dft8(const float2* x, float2* X){
  float2 s04=cadd(x[0],x[4]), d04=csub(x[0],x[4]);
  float2 s26=cadd(x[2],x[6]), d26=csub(x[2],x[6]);
  float2 s15=cadd(x[1],x[5]), d15=csub(x[1],x[5]);
  float2 s37=cadd(x[3],x[7]), d37=csub(x[3],x[7]);
  float2 wd26 = mulW4<SIGN>(d26);
  float2 wd37 = mulW4<SIGN>(d37);
  float2 E0=cadd(s04,s26), E2=csub(s04,s26), E1=cadd(d04,wd26), E3=csub(d04,wd26);
  float2 O0=cadd(s15,s37), O2=csub(s15,s37), O1=cadd(d15,wd37), O3=csub(d15,wd37);
  const float C=0.70710678118654752440f;
  float2 w1 = make_float2(C, SIGN*C);
  float2 w3 = make_float2(-C, SIGN*C);
  float2 a1 = cmul(w1, O1);
  float2 a2 = mulW4<SIGN>(O2);
  float2 a3 = cmul(w3, O3);
  X[0]=cadd(E0,O0); X[4]=csub(E0,O0);
  X[1]=cadd(E1,a1); X[5]=csub(E1,a1);
  X[2]=cadd(E2,a2); X[6]=csub(E2,a2);
  X[3]=cadd(E3,a3); X[7]=csub(E3,a3);
}

// 512-point FFT by one wave (64 lanes), radix-8^3 DIF.
// In:  v[a] = x[64*a + lane].  Out: v[a] = X[64*a + lane]  (same layout)
// buf: WAVE-PRIVATE LDS scratch, >= 576 float2. Per-wave DS ops execute in
// order at HW level; sched_barrier(0) fences compiler motion across phases.
template<int SIGN>
__device__ void fft512(float2 v[8], float2* buf, int lane){
  const float SGN = (float)SIGN;
  float sn, cs;
  float2 y[8];
  dft8<SIGN>(v, y);                          // over n2 -> k0
  __sincosf(SGN * 0.012271846303085130f * (float)lane, &sn, &cs);   // 2pi/512
  {
    float2 w1 = make_float2(cs, sn), w = w1;
    #pragma unroll
    for (int r=1;r<8;++r){ y[r] = cmul(y[r], w); w = cmul(w, w1); }
  }
  sb();
  #pragma unroll
  for (int r=0;r<8;++r) buf[72*r + lane] = y[r];
  sb();
  int k0 = lane >> 3, n0 = lane & 7;         // new lane = 8*k0 + n0
  float2 g[8];
  #pragma unroll
  for (int n1=0;n1<8;++n1) g[n1] = buf[72*k0 + 8*n1 + n0];
  float2 h[8];
  dft8<SIGN>(g, h);                          // over n1 -> k1
  __sincosf(SGN * 0.098174770424681039f * (float)n0, &sn, &cs);     // 2pi/64
  {
    float2 u1 = make_float2(cs, sn), w = u1;
    #pragma unroll
    for (int r=1;r<8;++r){ h[r] = cmul(h[r], w); w = cmul(w, u1); }
  }
  sb();
  #pragma unroll
  for (int r=0;r<8;++r) buf[72*n0 + 9*k0 + r] = h[r];
  sb();
  int k0r = lane & 7, k1r = lane >> 3;       // final lane = 8*k1 + k0
  float2 g2[8];
  #pragma unroll
  for (int m=0;m<8;++m) g2[m] = buf[72*m + 9*k0r + k1r];
  dft8<SIGN>(g2, v);                         // over n0 -> k2
}

// float <-> monotone uint for atomic min/max
__device__ __forceinline__ unsigned fenc(float f){
  unsigned u = __float_as_uint(f);
  return (u & 0x80000000u) ? ~u : (u | 0x80000000u);
}
__device__ __forceinline__ float fdec(unsigned e){
  return (e & 0x80000000u) ? __uint_as_float(e & 0x7FFFFFFFu) : __uint_as_float(~e);
}

// ---------------- kernels ----------------
__global__ void k_init(double* accum, unsigned* umin, unsigned* umax){
  int t = threadIdx.x;
  if (t == 0) *accum = 0.0;
  if (t < 2*NB){ umin[t] = 0xFFFFFFFFu; umax[t] = 0u; }
}

// rows (R2C): copy raw input to out left half; mf0; pack TWO real rows per
// complex FFT (z = m[2j] + i*m[2j+1]); Hermitian-unpack via one LDS mirror
// pass; store half-spectrum kx=0..255 per row, with the two REAL columns
// (kx=0 and kx=256) packed into stored column 0:
//   S[y][0] = (F(y,0), F(y,256)),  S[y][k] = F(y,k) for k=1..255.
// Per image: 512 x 256 complex = 1 MB (half of full-complex).
__global__ __launch_bounds__(256)
void k_row_fwd(const float* __restrict__ in0, const float* __restrict__ in1,
               float2* __restrict__ cplx, float* __restrict__ outp,
               int base, int Pc){
  __shared__ float2 xbuf[4][576];
  int wave = threadIdx.x >> 6, lane = threadIdx.x & 63;
  int g = blockIdx.x >> 4;          // local image [0, 2*Pc)
  int rowblk = blockIdx.x & 15;
  bool isin = (g < Pc);
  int b = base + (isin ? g : g - Pc);
  const float* src = (isin ? in0 : in1) + (size_t)b * IMG;
  float* outhalf = outp + (isin ? (size_t)0 : (size_t)NB*EL*1024) + (size_t)b * EL * 1024;
  float2* S = cplx + (size_t)g * (IMG/2);
  float2* buf = xbuf[wave];
  for (int i=0;i<4;++i){
    int j = rowblk*16 + wave*4 + i;          // packed row-pair index [0,256)
    int y1 = 2*j, y2 = 2*j + 1;
    const float* s1 = src + (size_t)y1*EL;
    const float* s2 = src + (size_t)y2*EL;
    float2 v[8];
    #pragma unroll
    for (int a=0;a<8;++a){
      float x1 = s1[64*a + lane];
      float x2 = s2[64*a + lane];
      outhalf[(size_t)y1*1024 + 64*a + lane] = x1;   // concat left half = raw input
      outhalf[(size_t)y2*1024 + 64*a + lane] = x2;
      v[a] = make_float2(__expf(-8.0f*x1*x1), __expf(-8.0f*x2*x2));  // soft_eq(x,0,.25)
    }
    fft512<-1>(v, buf, lane);                        // Z = R1 + i*R2
    sb();
    #pragma unroll
    for (int a=0;a<8;++a) buf[64*a + lane] = v[a];   // stage Z for mirror access
    sb();
    // R1(k) = (Z(k)+conj(Z(-k)))/2 ; R2(k) = (Z(k)-conj(Z(-k)))/(2i), k=0..255
    float2 f1[4], f2[4];
    #pragma unroll
    for (int a=0;a<4;++a){
      float2 m = buf[(512 - (64*a + lane)) & 511];
      f1[a] = make_float2(0.5f*(v[a].x + m.x), 0.5f*(v[a].y - m.y));
      f2[a] = make_float2(0.5f*(v[a].y + m.y), 0.5f*(m.x - v[a].x));
    }
    if (lane == 0){                                  // pack real (k=0,k=256):
      float2 znyq = buf[256];                        // Z(256)
      f1[0] = make_float2(v[0].x, znyq.x);           // (Re Z0, Re Z256)
      f2[0] = make_float2(v[0].y, znyq.y);           // (Im Z0, Im Z256)
    }
    float2* S1 = S + (size_t)y1*HC;
    float2* S2 = S + (size_t)y2*HC;
    #pragma unroll
    for (int a=0;a<4;++a){
      S1[64*a + lane] = f1[a];
      S2[64*a + lane] = f2[a];
    }
  }
}

// columns: 256 columns per image (half-spectrum). Normal columns k=1..255:
// fwd FFT -> |G|^2 -> inverse FFT. Column 0 is the packed real pair
// (kx=0, kx=256): fwd FFT, Hermitian-unpack G0/G256 via LDS mirror, square,
// repack u = P0 + i*P256 (both real), inverse FFT -> U(y) stored in col 0.
__global__ __launch_bounds__(128)
void k_col(float2* __restrict__ cplx){
  __shared__ float2 tile[8*580];
  int l = threadIdx.x;
  int wave = l >> 6, lane = l & 63;
  int g = blockIdx.x >> 5;
  int t = blockIdx.x & 31;
  int c0 = t*8;
  float2* S = cplx + (size_t)g*(IMG/2);
  {
    int cp = l & 3;              // column pair
    int rb = l >> 2;             // 32 rows per iteration
    for (int it=0; it<16; ++it){
      int r = rb + it*32;
      float4 v = *(const float4*)(S + (size_t)r*HC + c0 + 2*cp);
      tile[(2*cp+0)*580 + r] = make_float2(v.x, v.y);
      tile[(2*cp+1)*580 + r] = make_float2(v.z, v.w);
    }
  }
  __syncthreads();
  for (int cc=0; cc<4; ++cc){
    int c = wave*4 + cc;
    float2* slot = &tile[c*580];
    float2 v[8];
    #pragma unroll
    for (int a=0;a<8;++a) v[a] = slot[64*a + lane];
    fft512<-1>(v, slot, lane);                       // slot becomes scratch
    if (c0 + c == 0){
      // packed pair: W = G0 + i*G256, both Hermitian in ky
      sb();
      #pragma unroll
      for (int a=0;a<8;++a) slot[64*a + lane] = v[a];
      sb();
      #pragma unroll
      for (int a=0;a<8;++a){
        float2 m = slot[(512 - (64*a + lane)) & 511];        // W(-ky)
        float2 g0 = make_float2(0.5f*(v[a].x + m.x), 0.5f*(v[a].y - m.y));
        float2 gn = make_float2(0.5f*(v[a].y + m.y), 0.5f*(m.x - v[a].x));
        v[a] = make_float2(g0.x*g0.x + g0.y*g0.y, gn.x*gn.x + gn.y*gn.y); // P0+i*P256
      }
      sb();
    } else {
      #pragma unroll
      for (int a=0;a<8;++a)
        v[a] = make_float2(v[a].x*v[a].x + v[a].y*v[a].y, 0.f);  // |G|^2
    }
    fft512<1>(v, slot, lane);
    sb();
    #pragma unroll
    for (int a=0;a<8;++a) slot[64*a + lane] = v[a];
  }
  __syncthreads();
  {
    int cp = l & 3;
    int rb = l >> 2;
    for (int it=0; it<16; ++it){
      int r = rb + it*32;
      float2 e0 = tile[(2*cp+0)*580 + r];
      float2 e1 = tile[(2*cp+1)*580 + r];
      *(float4*)(S + (size_t)r*HC + c0 + 2*cp) = make_float4(e0.x, e0.y, e1.x, e1.y);
    }
  }
}

// rows (C2R): process row PAIRS (y, 512-y) (+ special pair (0,256)) so that
// both the kx-mirror (q(y,512-k)=conj(q(y,k))) and the packed-column-0 unpack
// (U(y)=q0(y)+i*q256(y), partner U((512-y)&511)) are wave-local. One inverse
// FFT of v(k)=q(y1,k)+i*q(y2,k) yields TWO real ac rows (Re->y1, Im->y2).
// Each S-row is read and written by exactly ONE wave -> ac lands in-place in
// NATURAL [y][x] float layout (ac row y = bytes of S row y), no barrier.
__global__ __launch_bounds__(256)
void k_row_inv(float2* __restrict__ cplx,
               unsigned* __restrict__ umin, unsigned* __restrict__ umax,
               int base, int Pc){
  __shared__ float2 xbuf[4][576];
  __shared__ float redmn[4], redmx[4];
  int wave = threadIdx.x >> 6, lane = threadIdx.x & 63;
  int g = blockIdx.x >> 4;
  int pblk = blockIdx.x & 15;
  float2* S = cplx + (size_t)g*(IMG/2);
  float* acb = (float*)S;
  float2* buf = xbuf[wave];
  const float SCALE = 1.0f / 68719476736.0f;   // 2^-36 : ifft2 norm * 1/(el*el)
  float mn = 3.4e38f, mx = -3.4e38f;
  for (int i=0;i<4;++i){
    int p = pblk*16 + wave*4 + i;              // pair index [0,256)
    int y1 = p;
    int y2 = (p == 0) ? 256 : 512 - p;
    const float2* S1 = S + (size_t)y1*HC;
    const float2* S2 = S + (size_t)y2*HC;
    #pragma unroll
    for (int a=0;a<4;++a){
      buf[64*a + lane]       = S1[64*a + lane];   // q(y1, 0..255)  [0]=U(y1)
      buf[256 + 64*a + lane] = S2[64*a + lane];   // q(y2, 0..255)  [256]=U(y2)
    }
    sb();
    float2 v[8];
    #pragma unroll
    for (int a=0;a<8;++a){
      int kx = 64*a + lane;
      if (a < 4){
        float2 q1 = buf[kx], q2 = buf[256 + kx];
        v[a] = make_float2(q1.x - q2.y, q1.y + q2.x);           // q1 + i*q2
      } else {
        int kxp = (512 - kx) & 511;                             // mirror 1..255
        float2 q1 = buf[kxp], q2 = buf[256 + kxp];
        v[a] = make_float2(q1.x + q2.y, q2.x - q1.y);           // conj(q1)+i*conj(q2)
      }
    }
    if (lane == 0){
      // unpack U: q0(y)=(U(y)+conj(U(py)))/2, q256(y)=-i/2*(U(y)-conj(U(py)))
      // partner py=(512-y)&511 is within the pair; (0,256) are self-partnered.
      float2 A = buf[0], B = buf[256];
      bool self = (y1 == 0);
      float2 PA = self ? A : B;
      float2 PB = self ? B : A;
      float2 q0a = make_float2(0.5f*(A.x + PA.x), 0.5f*(A.y - PA.y));
      float2 qna = make_float2(0.5f*(A.y + PA.y), 0.5f*(PA.x - A.x));
      float2 q0b = make_float2(0.5f*(B.x + PB.x), 0.5f*(B.y - PB.y));
      float2 qnb = make_float2(0.5f*(B.y + PB.y), 0.5f*(PB.x - B.x));
      v[0] = make_float2(q0a.x - q0b.y, q0a.y + q0b.x);         // kx=0
      v[4] = make_float2(qna.x - qnb.y, qna.y + qnb.x);         // kx=256
    }
    sb();
    fft512<1>(v, buf, lane);                   // Re = ac(y1,:), Im = ac(y2,:)
    float* d1 = acb + (size_t)y1*EL;
    float* d2 = acb + (size_t)y2*EL;
    #pragma unroll
    for (int a=0;a<8;++a){
      float a1 = v[a].x * SCALE;
      float a2 = v[a].y * SCALE;
      mn = fminf(mn, fminf(a1, a2)); mx = fmaxf(mx, fmaxf(a1, a2));
      d1[64*a + lane] = a1;
      d2[64*a + lane] = a2;
    }
  }
  for (int off=32; off>0; off>>=1){
    mn = fminf(mn, __shfl_down(mn, off, 64));
    mx = fmaxf(mx, __shfl_down(mx, off, 64));
  }
  if (lane==0){ redmn[wave]=mn; redmx[wave]=mx; }
  __syncthreads();
  if (threadIdx.x==0){
    mn = fminf(fminf(redmn[0],redmn[1]), fminf(redmn[2],redmn[3]));
    mx = fmaxf(fmaxf(redmx[0],redmx[1]), fmaxf(redmx[2],redmx[3]));
    int gid = (g < Pc) ? (base + g) : (NB + base + g - Pc);
    atomicMin(&umin[gid], fenc(mn));
    atomicMax(&umax[gid], fenc(mx));
  }
}

// shift + normalize + mask + write right halves + MSE accumulation.
// ac is in NATURAL [y][x] float layout inside each image's 1 MB region.
__global__ __launch_bounds__(256)
void k_final(const float2* __restrict__ cplx, const unsigned* __restrict__ umin,
             const unsigned* __restrict__ umax, float* __restrict__ outp,
             double* __restrict__ accum, int base, int Pc){
  __shared__ float red[4];
  int g    = blockIdx.x >> 5;      // local pair index [0,Pc)
  int part = blockIdx.x & 31;      // 16-row slice
  int b = base + g;
  float mni = fdec(umin[b]),      mxi = fdec(umax[b]);
  float mnt = fdec(umin[NB + b]), mxt = fdec(umax[NB + b]);
  float inv_i = 1.0f / (mxi - mni + 1e-12f);
  float inv_t = 1.0f / (mxt - mnt + 1e-12f);
  const float* ai_b = (const float*)(cplx + (size_t)g * (IMG/2));
  const float* at_b = (const float*)(cplx + (size_t)(Pc + g) * (IMG/2));
  float* o_i = outp;
  float* o_t = outp + (size_t)NB * 512 * 1024;
  float acc = 0.f;
  for (int it=0; it<8; ++it){
    int q = it*256 + threadIdx.x;        // [0,2048)
    int y = part*16 + (q >> 7);
    int x = (q & 127) * 4;
    int sy = (y + 256) & 511, sx = (x + 256) & 511;   // sx stays 4-aligned
    float4 ai = *(const float4*)(ai_b + (size_t)sy*EL + sx);
    float4 at = *(const float4*)(at_b + (size_t)sy*EL + sx);
    float dy = (float)(y - 256); float dy2 = dy*dy;
    float dx0 = (float)(x - 256);
    float m0 = __expf(-((dx0+0)*(dx0+0) + dy2) * 0.00125f);
    float m1 = __expf(-((dx0+1)*(dx0+1) + dy2) * 0.00125f);
    float m2 = __expf(-((dx0+2)*(dx0+2) + dy2) * 0.00125f);
    float m3 = __expf(-((dx0+3)*(dx0+3) + dy2) * 0.00125f);
    float4 oi, ot;
    oi.x = (ai.x - mni)*inv_i*m0; ot.x = (at.x - mnt)*inv_t*m0;
    oi.y = (ai.y - mni)*inv_i*m1; ot.y = (at.y - mnt)*inv_t*m1;
    oi.z = (ai.z - mni)*inv_i*m2; ot.z = (at.z - mnt)*inv_t*m2;
    oi.w = (ai.w - mni)*inv_i*m3; ot.w = (at.w - mnt)*inv_t*m3;
    size_t rowo = ((size_t)b * 512 + (size_t)y) * 1024 + 512 + x;
    *(float4*)(o_i + 1 + rowo) = oi;   // +1: out[0] is the scalar loss
    *(float4*)(o_t + 1 + rowo) = ot;
    float d0 = oi.x - ot.x, d1 = oi.y - ot.y, d2 = oi.z - ot.z, d3 = oi.w - ot.w;
    acc += d0*d0 + d1*d1 + d2*d2 + d3*d3;
  }
  for (int off=32; off>0; off>>=1) acc += __shfl_down(acc, off, 64);
  int wave = threadIdx.x>>6, lane = threadIdx.x&63;
  if (lane==0) red[wave]=acc;
  __syncthreads();
  if (threadIdx.x==0) atomicAdd(accum, (double)(red[0]+red[1]+red[2]+red[3]));
}

__global__ void k_div(const double* accum, float* out0){
  out0[0] = (float)(*accum / 16777216.0);   // mean over 64*512*512
}

// ---------------- launch ----------------
extern "C" void kernel_launch(void* const* d_in, const int* in_sizes, int n_in,
                              void* d_out, int out_size, void* d_ws, size_t ws_size,
                              hipStream_t stream){
  (void)in_sizes; (void)n_in; (void)out_size;
  const float* in0 = (const float*)d_in[0];
  const float* in1 = (const float*)d_in[1];
  float* out = (float*)d_out;
  char* ws = (char*)d_ws;
  double*   accum = (double*)ws;
  unsigned* umin  = (unsigned*)(ws + 512);
  unsigned* umax  = (unsigned*)(ws + 1024);
  float2*   cplx  = (float2*)(ws + 4096);

  size_t avail = ws_size > 4096 ? ws_size - 4096 : 0;
  int P = (int)(avail / (2ull * 1024ull * 1024ull));  // 2 MB per image-pair (half-spectrum in+tgt)
  if (P > NB) P = NB;
  if (P < 1)  P = 1;

  k_init<<<dim3(1), dim3(128), 0, stream>>>(accum, umin, umax);
  float* out1 = out + 1;
  for (int base = 0; base < NB; base += P){
    int Pc = (NB - base < P) ? (NB - base) : P;
    k_row_fwd<<<dim3(2*Pc*16), dim3(256), 0, stream>>>(in0, in1, cplx, out1, base, Pc);
    k_col    <<<dim3(2*Pc*32), dim3(128), 0, stream>>>(cplx);
    k_row_inv<<<dim3(2*Pc*16), dim3(256), 0, stream>>>(cplx, umin, umax, base, Pc);
    k_final  <<<dim3(Pc*32),   dim3(256), 0, stream>>>(cplx, umin, umax, out, accum, base, Pc);
  }
  k_div<<<dim3(1), dim3(1), 0, stream>>>(accum, out);
}

// Round 3
// 555.152 us; speedup vs baseline: 1.0111x; 1.0111x over previous
//
#include <hip/hip_runtime.h>

#define EL 512
#define NB 64
#define IMG (EL*EL)
#define HC 256   // stored half-spectrum width (complex) per row; col 0 packs (kx=0, kx=256)

__device__ __forceinline__ void sb(){ __builtin_amdgcn_sched_barrier(0); }

// ---------------- complex helpers ----------------
__device__ __forceinline__ float2 cadd(float2 a, float2 b){ return make_float2(a.x+b.x, a.y+b.y); }
__device__ __forceinline__ float2 csub(float2 a, float2 b){ return make_float2(a.x-b.x, a.y-b.y); }
__device__ __forceinline__ float2 cmul(float2 a, float2 b){ return make_float2(a.x*b.x - a.y*b.y, a.x*b.y + a.y*b.x); }

template<int SIGN> __device__ __forceinline__ float2 mulW4(float2 a);
template<> __device__ __forceinline__ float2 mulW4<-1>(float2 a){ return make_float2( a.y, -a.x); } // * -i
template<> __device__ __forceinline__ float2 mulW4< 1>(float2 a){ return make_float2(-a.y,  a.x); } // * +i

// 8-point DFT, SIGN=-1 forward, +1 inverse (unnormalized)
template<int SIGN>
__device__ __forceinline__ void dft8(const float2* x, float2* X){
  float2 s04=cadd(x[0],x[4]), d04=csub(x[0],x[4]);
  float2 s26=cadd(x[2],x[6]), d26=csub(x[2],x[6]);
  float2 s15=cadd(x[1],x[5]), d15=csub(x[1],x[5]);
  float2 s37=cadd(x[3],x[7]), d37=csub(x[3],x[7]);
  float2 wd26 = mulW4<SIGN>(d26);
  float2 wd37 = mulW4<SIGN>(d37);
  float2 E0=cadd(s04,s26), E2=csub(s04,s26), E1=cadd(d04,wd26), E3=csub(d04,wd26);
  float2 O0=cadd(s15,s37), O2=csub(s15,s37), O1=cadd(d15,wd37), O3=csub(d15,wd37);
  const float C=0.70710678118654752440f;
  float2 w1 = make_float2(C, SIGN*C);
  float2 w3 = make_float2(-C, SIGN*C);
  float2 a1 = cmul(w1, O1);
  float2 a2 = mulW4<SIGN>(O2);
  float2 a3 = cmul(w3, O3);
  X[0]=cadd(E0,O0); X[4]=csub(E0,O0);
  X[1]=cadd(E1,a1); X[5]=csub(E1,a1);
  X[2]=cadd(E2,a2); X[6]=csub(E2,a2);
  X[3]=cadd(E3,a3); X[7]=csub(E3,a3);
}

// apply w1^r to y[r], r=1..7, via log-depth binary powering (dep depth 3,
// all apply-cmuls independent) instead of a 7-deep serial chain.
__device__ __forceinline__ void twiddle8(float2 y[8], float cs, float sn){
  float2 w1 = make_float2(cs, sn);
  float2 w2 = cmul(w1, w1);
  float2 w3 = cmul(w2, w1);
  float2 w4 = cmul(w2, w2);
  float2 w5 = cmul(w4, w1);
  float2 w6 = cmul(w4, w2);
  float2 w7 = cmul(w4, w3);
  y[1] = cmul(y[1], w1);
  y[2] = cmul(y[2], w2);
  y[3] = cmul(y[3], w3);
  y[4] = cmul(y[4], w4);
  y[5] = cmul(y[5], w5);
  y[6] = cmul(y[6], w6);
  y[7] = cmul(y[7], w7);
}

// 512-point FFT by one wave (64 lanes), radix-8^3 DIF.
// In:  v[a] = x[64*a + lane].  Out: v[a] = X[64*a + lane]  (same layout)
// buf: WAVE-PRIVATE LDS scratch, >= 576 float2. Per-wave DS ops execute in
// order at HW level; sched_barrier(0) fences compiler motion across phases.
template<int SIGN>
__device__ void fft512(float2 v[8], float2* buf, int lane){
  const float SGN = (float)SIGN;
  float sn, cs;
  float2 y[8];
  dft8<SIGN>(v, y);                          // over n2 -> k0
  __sincosf(SGN * 0.012271846303085130f * (float)lane, &sn, &cs);   // 2pi/512
  twiddle8(y, cs, sn);
  sb();
  #pragma unroll
  for (int r=0;r<8;++r) buf[72*r + lane] = y[r];
  sb();
  int k0 = lane >> 3, n0 = lane & 7;         // new lane = 8*k0 + n0
  float2 g[8];
  #pragma unroll
  for (int n1=0;n1<8;++n1) g[n1] = buf[72*k0 + 8*n1 + n0];
  float2 h[8];
  dft8<SIGN>(g, h);                          // over n1 -> k1
  __sincosf(SGN * 0.098174770424681039f * (float)n0, &sn, &cs);     // 2pi/64
  twiddle8(h, cs, sn);
  sb();
  #pragma unroll
  for (int r=0;r<8;++r) buf[72*n0 + 9*k0 + r] = h[r];
  sb();
  int k0r = lane & 7, k1r = lane >> 3;       // final lane = 8*k1 + k0
  float2 g2[8];
  #pragma unroll
  for (int m=0;m<8;++m) g2[m] = buf[72*m + 9*k0r + k1r];
  dft8<SIGN>(g2, v);                         // over n0 -> k2
}

// float <-> monotone uint for atomic min/max
__device__ __forceinline__ unsigned fenc(float f){
  unsigned u = __float_as_uint(f);
  return (u & 0x80000000u) ? ~u : (u | 0x80000000u);
}
__device__ __forceinline__ float fdec(unsigned e){
  return (e & 0x80000000u) ? __uint_as_float(e & 0x7FFFFFFFu) : __uint_as_float(~e);
}

// ---------------- kernels ----------------
__global__ void k_init(double* accum, unsigned* umin, unsigned* umax){
  int t = threadIdx.x;
  if (t == 0) *accum = 0.0;
  if (t < 2*NB){ umin[t] = 0xFFFFFFFFu; umax[t] = 0u; }
}

// rows (R2C): copy raw input to out left half; mf0; pack TWO real rows per
// complex FFT (z = m[2j] + i*m[2j+1]); Hermitian-unpack via one LDS mirror
// pass; store half-spectrum kx=0..255 per row, with the two REAL columns
// (kx=0 and kx=256) packed into stored column 0:
//   S[y][0] = (F(y,0), F(y,256)),  S[y][k] = F(y,k) for k=1..255.
// Per image: 512 x 256 complex = 1 MB (half of full-complex).
__global__ __launch_bounds__(256)
void k_row_fwd(const float* __restrict__ in0, const float* __restrict__ in1,
               float2* __restrict__ cplx, float* __restrict__ outp,
               int base, int Pc){
  __shared__ float2 xbuf[4][576];
  int wave = threadIdx.x >> 6, lane = threadIdx.x & 63;
  int g = blockIdx.x >> 4;          // local image [0, 2*Pc)
  int rowblk = blockIdx.x & 15;
  bool isin = (g < Pc);
  int b = base + (isin ? g : g - Pc);
  const float* src = (isin ? in0 : in1) + (size_t)b * IMG;
  float* outhalf = outp + (isin ? (size_t)0 : (size_t)NB*EL*1024) + (size_t)b * EL * 1024;
  float2* S = cplx + (size_t)g * (IMG/2);
  float2* buf = xbuf[wave];
  for (int i=0;i<4;++i){
    int j = rowblk*16 + wave*4 + i;          // packed row-pair index [0,256)
    int y1 = 2*j, y2 = 2*j + 1;
    const float* s1 = src + (size_t)y1*EL;
    const float* s2 = src + (size_t)y2*EL;
    float2 v[8];
    #pragma unroll
    for (int a=0;a<8;++a){
      float x1 = s1[64*a + lane];
      float x2 = s2[64*a + lane];
      outhalf[(size_t)y1*1024 + 64*a + lane] = x1;   // concat left half = raw input
      outhalf[(size_t)y2*1024 + 64*a + lane] = x2;
      v[a] = make_float2(__expf(-8.0f*x1*x1), __expf(-8.0f*x2*x2));  // soft_eq(x,0,.25)
    }
    fft512<-1>(v, buf, lane);                        // Z = R1 + i*R2
    sb();
    #pragma unroll
    for (int a=0;a<8;++a) buf[64*a + lane] = v[a];   // stage Z for mirror access
    sb();
    // R1(k) = (Z(k)+conj(Z(-k)))/2 ; R2(k) = (Z(k)-conj(Z(-k)))/(2i), k=0..255
    float2 f1[4], f2[4];
    #pragma unroll
    for (int a=0;a<4;++a){
      float2 m = buf[(512 - (64*a + lane)) & 511];
      f1[a] = make_float2(0.5f*(v[a].x + m.x), 0.5f*(v[a].y - m.y));
      f2[a] = make_float2(0.5f*(v[a].y + m.y), 0.5f*(m.x - v[a].x));
    }
    if (lane == 0){                                  // pack real (k=0,k=256):
      float2 znyq = buf[256];                        // Z(256)
      f1[0] = make_float2(v[0].x, znyq.x);           // (Re Z0, Re Z256)
      f2[0] = make_float2(v[0].y, znyq.y);           // (Im Z0, Im Z256)
    }
    float2* S1 = S + (size_t)y1*HC;
    float2* S2 = S + (size_t)y2*HC;
    #pragma unroll
    for (int a=0;a<4;++a){
      S1[64*a + lane] = f1[a];
      S2[64*a + lane] = f2[a];
    }
  }
}

// columns: 256 columns per image (half-spectrum), 8 per block, 4 waves x 2.
// Normal columns k=1..255: fwd FFT -> |G|^2 -> inverse FFT. Column 0 is the
// packed real pair (kx=0, kx=256): fwd FFT, Hermitian-unpack G0/G256 via LDS
// mirror, square, repack u = P0 + i*P256 (both real), inverse FFT -> col 0.
// 256 threads (vs 128 before): LDS/block unchanged (37 KB -> 4 blocks/CU),
// so occupancy doubles to 16 waves/CU (4/SIMD) to hide FFT LDS latency.
__global__ __launch_bounds__(256)
void k_col(float2* __restrict__ cplx){
  __shared__ float2 tile[8*580];
  int l = threadIdx.x;
  int wave = l >> 6, lane = l & 63;
  int g = blockIdx.x >> 5;
  int t = blockIdx.x & 31;
  int c0 = t*8;
  float2* S = cplx + (size_t)g*(IMG/2);
  {
    int cp = l & 3;              // column pair (2 cols per float4)
    int rb = l >> 2;             // 64 rows per iteration
    for (int it=0; it<8; ++it){
      int r = rb + it*64;
      float4 v = *(const float4*)(S + (size_t)r*HC + c0 + 2*cp);
      tile[(2*cp+0)*580 + r] = make_float2(v.x, v.y);
      tile[(2*cp+1)*580 + r] = make_float2(v.z, v.w);
    }
  }
  __syncthreads();
  for (int cc=0; cc<2; ++cc){
    int c = wave*2 + cc;
    float2* slot = &tile[c*580];
    float2 v[8];
    #pragma unroll
    for (int a=0;a<8;++a) v[a] = slot[64*a + lane];
    fft512<-1>(v, slot, lane);                       // slot becomes scratch
    if (c0 + c == 0){
      // packed pair: W = G0 + i*G256, both Hermitian in ky
      sb();
      #pragma unroll
      for (int a=0;a<8;++a) slot[64*a + lane] = v[a];
      sb();
      #pragma unroll
      for (int a=0;a<8;++a){
        float2 m = slot[(512 - (64*a + lane)) & 511];        // W(-ky)
        float2 g0 = make_float2(0.5f*(v[a].x + m.x), 0.5f*(v[a].y - m.y));
        float2 gn = make_float2(0.5f*(v[a].y + m.y), 0.5f*(m.x - v[a].x));
        v[a] = make_float2(g0.x*g0.x + g0.y*g0.y, gn.x*gn.x + gn.y*gn.y); // P0+i*P256
      }
      sb();
    } else {
      #pragma unroll
      for (int a=0;a<8;++a)
        v[a] = make_float2(v[a].x*v[a].x + v[a].y*v[a].y, 0.f);  // |G|^2
    }
    fft512<1>(v, slot, lane);
    sb();
    #pragma unroll
    for (int a=0;a<8;++a) slot[64*a + lane] = v[a];
  }
  __syncthreads();
  {
    int cp = l & 3;
    int rb = l >> 2;
    for (int it=0; it<8; ++it){
      int r = rb + it*64;
      float2 e0 = tile[(2*cp+0)*580 + r];
      float2 e1 = tile[(2*cp+1)*580 + r];
      *(float4*)(S + (size_t)r*HC + c0 + 2*cp) = make_float4(e0.x, e0.y, e1.x, e1.y);
    }
  }
}

// rows (C2R): process row PAIRS (y, 512-y) (+ special pair (0,256)) so that
// both the kx-mirror (q(y,512-k)=conj(q(y,k))) and the packed-column-0 unpack
// (U(y)=q0(y)+i*q256(y), partner U((512-y)&511)) are wave-local. One inverse
// FFT of v(k)=q(y1,k)+i*q(y2,k) yields TWO real ac rows (Re->y1, Im->y2).
// Each S-row is read and written by exactly ONE wave -> ac lands in-place in
// NATURAL [y][x] float layout (ac row y = bytes of S row y), no barrier.
__global__ __launch_bounds__(256)
void k_row_inv(float2* __restrict__ cplx,
               unsigned* __restrict__ umin, unsigned* __restrict__ umax,
               int base, int Pc){
  __shared__ float2 xbuf[4][576];
  __shared__ float redmn[4], redmx[4];
  int wave = threadIdx.x >> 6, lane = threadIdx.x & 63;
  int g = blockIdx.x >> 4;
  int pblk = blockIdx.x & 15;
  float2* S = cplx + (size_t)g*(IMG/2);
  float* acb = (float*)S;
  float2* buf = xbuf[wave];
  const float SCALE = 1.0f / 68719476736.0f;   // 2^-36 : ifft2 norm * 1/(el*el)
  float mn = 3.4e38f, mx = -3.4e38f;
  for (int i=0;i<4;++i){
    int p = pblk*16 + wave*4 + i;              // pair index [0,256)
    int y1 = p;
    int y2 = (p == 0) ? 256 : 512 - p;
    const float2* S1 = S + (size_t)y1*HC;
    const float2* S2 = S + (size_t)y2*HC;
    #pragma unroll
    for (int a=0;a<4;++a){
      buf[64*a + lane]       = S1[64*a + lane];   // q(y1, 0..255)  [0]=U(y1)
      buf[256 + 64*a + lane] = S2[64*a + lane];   // q(y2, 0..255)  [256]=U(y2)
    }
    sb();
    float2 v[8];
    #pragma unroll
    for (int a=0;a<8;++a){
      int kx = 64*a + lane;
      if (a < 4){
        float2 q1 = buf[kx], q2 = buf[256 + kx];
        v[a] = make_float2(q1.x - q2.y, q1.y + q2.x);           // q1 + i*q2
      } else {
        int kxp = (512 - kx) & 511;                             // mirror 1..255
        float2 q1 = buf[kxp], q2 = buf[256 + kxp];
        v[a] = make_float2(q1.x + q2.y, q2.x - q1.y);           // conj(q1)+i*conj(q2)
      }
    }
    if (lane == 0){
      // unpack U: q0(y)=(U(y)+conj(U(py)))/2, q256(y)=-i/2*(U(y)-conj(U(py)))
      // partner py=(512-y)&511 is within the pair; (0,256) are self-partnered.
      float2 A = buf[0], B = buf[256];
      bool self = (y1 == 0);
      float2 PA = self ? A : B;
      float2 PB = self ? B : A;
      float2 q0a = make_float2(0.5f*(A.x + PA.x), 0.5f*(A.y - PA.y));
      float2 qna = make_float2(0.5f*(A.y + PA.y), 0.5f*(PA.x - A.x));
      float2 q0b = make_float2(0.5f*(B.x + PB.x), 0.5f*(B.y - PB.y));
      float2 qnb = make_float2(0.5f*(B.y + PB.y), 0.5f*(PB.x - B.x));
      v[0] = make_float2(q0a.x - q0b.y, q0a.y + q0b.x);         // kx=0
      v[4] = make_float2(qna.x - qnb.y, qna.y + qnb.x);         // kx=256
    }
    sb();
    fft512<1>(v, buf, lane);                   // Re = ac(y1,:), Im = ac(y2,:)
    float* d1 = acb + (size_t)y1*EL;
    float* d2 = acb + (size_t)y2*EL;
    #pragma unroll
    for (int a=0;a<8;++a){
      float a1 = v[a].x * SCALE;
      float a2 = v[a].y * SCALE;
      mn = fminf(mn, fminf(a1, a2)); mx = fmaxf(mx, fmaxf(a1, a2));
      d1[64*a + lane] = a1;
      d2[64*a + lane] = a2;
    }
  }
  for (int off=32; off>0; off>>=1){
    mn = fminf(mn, __shfl_down(mn, off, 64));
    mx = fmaxf(mx, __shfl_down(mx, off, 64));
  }
  if (lane==0){ redmn[wave]=mn; redmx[wave]=mx; }
  __syncthreads();
  if (threadIdx.x==0){
    mn = fminf(fminf(redmn[0],redmn[1]), fminf(redmn[2],redmn[3]));
    mx = fmaxf(fmaxf(redmx[0],redmx[1]), fmaxf(redmx[2],redmx[3]));
    int gid = (g < Pc) ? (base + g) : (NB + base + g - Pc);
    atomicMin(&umin[gid], fenc(mn));
    atomicMax(&umax[gid], fenc(mx));
  }
}

// shift + normalize + mask + write right halves + MSE accumulation.
// ac is in NATURAL [y][x] float layout inside each image's 1 MB region.
__global__ __launch_bounds__(256)
void k_final(const float2* __restrict__ cplx, const unsigned* __restrict__ umin,
             const unsigned* __restrict__ umax, float* __restrict__ outp,
             double* __restrict__ accum, int base, int Pc){
  __shared__ float red[4];
  int g    = blockIdx.x >> 5;      // local pair index [0,Pc)
  int part = blockIdx.x & 31;      // 16-row slice
  int b = base + g;
  float mni = fdec(umin[b]),      mxi = fdec(umax[b]);
  float mnt = fdec(umin[NB + b]), mxt = fdec(umax[NB + b]);
  float inv_i = 1.0f / (mxi - mni + 1e-12f);
  float inv_t = 1.0f / (mxt - mnt + 1e-12f);
  const float* ai_b = (const float*)(cplx + (size_t)g * (IMG/2));
  const float* at_b = (const float*)(cplx + (size_t)(Pc + g) * (IMG/2));
  float* o_i = outp;
  float* o_t = outp + (size_t)NB * 512 * 1024;
  float acc = 0.f;
  for (int it=0; it<8; ++it){
    int q = it*256 + threadIdx.x;        // [0,2048)
    int y = part*16 + (q >> 7);
    int x = (q & 127) * 4;
    int sy = (y + 256) & 511, sx = (x + 256) & 511;   // sx stays 4-aligned
    float4 ai = *(const float4*)(ai_b + (size_t)sy*EL + sx);
    float4 at = *(const float4*)(at_b + (size_t)sy*EL + sx);
    float dy = (float)(y - 256); float dy2 = dy*dy;
    float dx0 = (float)(x - 256);
    float m0 = __expf(-((dx0+0)*(dx0+0) + dy2) * 0.00125f);
    float m1 = __expf(-((dx0+1)*(dx0+1) + dy2) * 0.00125f);
    float m2 = __expf(-((dx0+2)*(dx0+2) + dy2) * 0.00125f);
    float m3 = __expf(-((dx0+3)*(dx0+3) + dy2) * 0.00125f);
    float4 oi, ot;
    oi.x = (ai.x - mni)*inv_i*m0; ot.x = (at.x - mnt)*inv_t*m0;
    oi.y = (ai.y - mni)*inv_i*m1; ot.y = (at.y - mnt)*inv_t*m1;
    oi.z = (ai.z - mni)*inv_i*m2; ot.z = (at.z - mnt)*inv_t*m2;
    oi.w = (ai.w - mni)*inv_i*m3; ot.w = (at.w - mnt)*inv_t*m3;
    size_t rowo = ((size_t)b * 512 + (size_t)y) * 1024 + 512 + x;
    *(float4*)(o_i + 1 + rowo) = oi;   // +1: out[0] is the scalar loss
    *(float4*)(o_t + 1 + rowo) = ot;
    float d0 = oi.x - ot.x, d1 = oi.y - ot.y, d2 = oi.z - ot.z, d3 = oi.w - ot.w;
    acc += d0*d0 + d1*d1 + d2*d2 + d3*d3;
  }
  for (int off=32; off>0; off>>=1) acc += __shfl_down(acc, off, 64);
  int wave = threadIdx.x>>6, lane = threadIdx.x&63;
  if (lane==0) red[wave]=acc;
  __syncthreads();
  if (threadIdx.x==0) atomicAdd(accum, (double)(red[0]+red[1]+red[2]+red[3]));
}

__global__ void k_div(const double* accum, float* out0){
  out0[0] = (float)(*accum / 16777216.0);   // mean over 64*512*512
}

// ---------------- launch ----------------
extern "C" void kernel_launch(void* const* d_in, const int* in_sizes, int n_in,
                              void* d_out, int out_size, void* d_ws, size_t ws_size,
                              hipStream_t stream){
  (void)in_sizes; (void)n_in; (void)out_size;
  const float* in0 = (const float*)d_in[0];
  const float* in1 = (const float*)d_in[1];
  float* out = (float*)d_out;
  char* ws = (char*)d_ws;
  double*   accum = (double*)ws;
  unsigned* umin  = (unsigned*)(ws + 512);
  unsigned* umax  = (unsigned*)(ws + 1024);
  float2*   cplx  = (float2*)(ws + 4096);

  size_t avail = ws_size > 4096 ? ws_size - 4096 : 0;
  int P = (int)(avail / (2ull * 1024ull * 1024ull));  // 2 MB per image-pair (half-spectrum in+tgt)
  if (P > NB) P = NB;
  if (P < 1)  P = 1;

  k_init<<<dim3(1), dim3(128), 0, stream>>>(accum, umin, umax);
  float* out1 = out + 1;
  for (int base = 0; base < NB; base += P){
    int Pc = (NB - base < P) ? (NB - base) : P;
    k_row_fwd<<<dim3(2*Pc*16), dim3(256), 0, stream>>>(in0, in1, cplx, out1, base, Pc);
    k_col    <<<dim3(2*Pc*32), dim3(256), 0, stream>>>(cplx);
    k_row_inv<<<dim3(2*Pc*16), dim3(256), 0, stream>>>(cplx, umin, umax, base, Pc);
    k_final  <<<dim3(Pc*32),   dim3(256), 0, stream>>>(cplx, umin, umax, out, accum, base, Pc);
  }
  k_div<<<dim3(1), dim3(1), 0, stream>>>(accum, out);
}